// Round 1
// baseline (1554.609 us; speedup 1.0000x reference)
//
#include <hip/hip_runtime.h>
#include <math.h>

#define N_NODES 50000
#define N_EDGES 500000
#define IN_DIM  128
#define NH      8
#define HD      16
#define OUTD    128   // NH*HD
#define CLAMP_V 5.0f

// ---------------------------------------------------------------------------
// Kernel 1: node GEMM.  C-tile 64 nodes x 64 cols.  grid.y in [0,6):
//   y/2 selects W (0=Q,1=K,2=V), y%2 selects column half of the 128 cols.
// Q goes straight into d_out's Vo region (Vo is initialized to Qh).
// ---------------------------------------------------------------------------
__global__ __launch_bounds__(256) void node_gemm_kernel(
    const float* __restrict__ x,
    const float* __restrict__ WQ, const float* __restrict__ bQ,
    const float* __restrict__ WK, const float* __restrict__ bK,
    const float* __restrict__ WV, const float* __restrict__ bV,
    float* __restrict__ Vo, float* __restrict__ Kh, float* __restrict__ Vh)
{
    __shared__ float A[64][132];   // 64 rows x 128 K, padded stride
    __shared__ float B[64][64];    // 64 K x 64 cols (half of K at a time)

    const int t  = threadIdx.x;
    const int bx = blockIdx.x;
    const int by = blockIdx.y;
    const int which = by >> 1;
    const int ch    = (by & 1) * 64;

    const float* W    = (which == 0) ? WQ : (which == 1 ? WK : WV);
    const float* bias = (which == 0) ? bQ : (which == 1 ? bK : bV);
    float*       out  = (which == 0) ? Vo : (which == 1 ? Kh : Vh);

    const int r0 = bx * 64;

    // Load A tile: 64 rows x 128 cols (float4, coalesced; zero-pad tail rows)
    #pragma unroll
    for (int it = 0; it < 8; ++it) {
        int idx = it * 256 + t;          // 0..2047
        int k4  = idx & 31;              // 0..31
        int r   = idx >> 5;              // 0..63
        float4 v = make_float4(0.f, 0.f, 0.f, 0.f);
        if (r0 + r < N_NODES)
            v = *(const float4*)(x + (size_t)(r0 + r) * IN_DIM + k4 * 4);
        *(float4*)&A[r][k4 * 4] = v;
    }

    const int tx = t & 15, ty = t >> 4;
    float acc[4][4] = {};

    for (int kh = 0; kh < 2; ++kh) {
        __syncthreads();
        // Load B half: rows kh*64..kh*64+63, cols ch..ch+63
        #pragma unroll
        for (int it = 0; it < 4; ++it) {
            int idx = it * 256 + t;      // 0..1023
            int c4  = idx & 15;
            int kk  = idx >> 4;          // 0..63
            float4 v = *(const float4*)(W + (size_t)(kh * 64 + kk) * 128 + ch + c4 * 4);
            *(float4*)&B[kk][c4 * 4] = v;
        }
        __syncthreads();

        #pragma unroll 4
        for (int k = 0; k < 64; k += 4) {
            float4 a4[4], b4[4];
            a4[0] = *(const float4*)&A[ty * 4 + 0][kh * 64 + k];
            a4[1] = *(const float4*)&A[ty * 4 + 1][kh * 64 + k];
            a4[2] = *(const float4*)&A[ty * 4 + 2][kh * 64 + k];
            a4[3] = *(const float4*)&A[ty * 4 + 3][kh * 64 + k];
            b4[0] = *(const float4*)&B[k + 0][tx * 4];
            b4[1] = *(const float4*)&B[k + 1][tx * 4];
            b4[2] = *(const float4*)&B[k + 2][tx * 4];
            b4[3] = *(const float4*)&B[k + 3][tx * 4];
            const float* aa = (const float*)a4;  // aa[i*4+kk]
            const float* bb = (const float*)b4;  // bb[kk*4+j]
            #pragma unroll
            for (int kk = 0; kk < 4; ++kk)
                #pragma unroll
                for (int i = 0; i < 4; ++i)
                    #pragma unroll
                    for (int j = 0; j < 4; ++j)
                        acc[i][j] += aa[i * 4 + kk] * bb[kk * 4 + j];
        }
    }

    // Epilogue: write C tile with bias
    #pragma unroll
    for (int i = 0; i < 4; ++i) {
        int r = r0 + ty * 4 + i;
        if (r < N_NODES) {
            #pragma unroll
            for (int j = 0; j < 4; ++j) {
                int c = ch + tx * 4 + j;
                out[(size_t)r * OUTD + c] = acc[i][j] + bias[c];
            }
        }
    }
}

// ---------------------------------------------------------------------------
// Kernel 2: edge GEMM + fused epilogue.
// C-tile: 64 edges x 64 cols of Ex (= 2 complete heads since head h owns
// cols [h*32, h*32+32)).  Epilogue computes conn, score, exp, denom-atomics.
// ---------------------------------------------------------------------------
__global__ __launch_bounds__(256) void edge_kernel(
    const float* __restrict__ edge_attr,
    const int*   __restrict__ edge_index,
    const float* __restrict__ WE, const float* __restrict__ bE,
    const float* __restrict__ Aw,
    const float* __restrict__ Qh,     // = Vo region of d_out
    const float* __restrict__ Kh,
    float* __restrict__ conn_out,     // d_out + N*128
    float* __restrict__ exp_s,
    float* __restrict__ denom)
{
    __shared__ float A[64][132];
    __shared__ float B[64][64];

    const int t  = threadIdx.x;
    const int e0 = blockIdx.x * 64;
    const int c0 = blockIdx.y * 64;   // col offset within 256

    // Load A tile (edge_attr rows e0..e0+63)
    #pragma unroll
    for (int it = 0; it < 8; ++it) {
        int idx = it * 256 + t;
        int k4  = idx & 31;
        int r   = idx >> 5;
        float4 v = make_float4(0.f, 0.f, 0.f, 0.f);
        if (e0 + r < N_EDGES)
            v = *(const float4*)(edge_attr + (size_t)(e0 + r) * IN_DIM + k4 * 4);
        *(float4*)&A[r][k4 * 4] = v;
    }

    const int tx = t & 15, ty = t >> 4;
    float acc[4][4] = {};

    for (int kh = 0; kh < 2; ++kh) {
        __syncthreads();
        #pragma unroll
        for (int it = 0; it < 4; ++it) {
            int idx = it * 256 + t;
            int c4  = idx & 15;
            int kk  = idx >> 4;
            float4 v = *(const float4*)(WE + (size_t)(kh * 64 + kk) * 256 + c0 + c4 * 4);
            *(float4*)&B[kk][c4 * 4] = v;
        }
        __syncthreads();

        #pragma unroll 4
        for (int k = 0; k < 64; k += 4) {
            float4 a4[4], b4[4];
            a4[0] = *(const float4*)&A[ty * 4 + 0][kh * 64 + k];
            a4[1] = *(const float4*)&A[ty * 4 + 1][kh * 64 + k];
            a4[2] = *(const float4*)&A[ty * 4 + 2][kh * 64 + k];
            a4[3] = *(const float4*)&A[ty * 4 + 3][kh * 64 + k];
            b4[0] = *(const float4*)&B[k + 0][tx * 4];
            b4[1] = *(const float4*)&B[k + 1][tx * 4];
            b4[2] = *(const float4*)&B[k + 2][tx * 4];
            b4[3] = *(const float4*)&B[k + 3][tx * 4];
            const float* aa = (const float*)a4;
            const float* bb = (const float*)b4;
            #pragma unroll
            for (int kk = 0; kk < 4; ++kk)
                #pragma unroll
                for (int i = 0; i < 4; ++i)
                    #pragma unroll
                    for (int j = 0; j < 4; ++j)
                        acc[i][j] += aa[i * 4 + kk] * bb[kk * 4 + j];
        }
    }
    __syncthreads();   // all reads of A done; reuse A as the Ex tile

    // Stash Ex tile (with bias) into LDS
    #pragma unroll
    for (int i = 0; i < 4; ++i)
        #pragma unroll
        for (int j = 0; j < 4; ++j)
            A[ty * 4 + i][tx * 4 + j] = acc[i][j] + bE[c0 + tx * 4 + j];
    __syncthreads();

    // Epilogue: 128 threads -> (edge-in-tile, head-local)
    if (t < 128) {
        const int r  = t >> 1;
        const int hl = t & 1;
        const int e  = e0 + r;
        if (e < N_EDGES) {
            const int h   = (c0 >> 5) + hl;       // global head
            const int src = edge_index[e];
            const int dst = edge_index[N_EDGES + e];

            const float4* K4 = (const float4*)(Kh + (size_t)src * OUTD + h * HD);
            const float4* Q4 = (const float4*)(Qh + (size_t)dst * OUTD + h * HD);
            float kq[16];
            #pragma unroll
            for (int i = 0; i < 4; ++i) {
                float4 kk = K4[i], qq = Q4[i];
                kq[i * 4 + 0] = kk.x + qq.x;
                kq[i * 4 + 1] = kk.y + qq.y;
                kq[i * 4 + 2] = kk.z + qq.z;
                kq[i * 4 + 3] = kk.w + qq.w;
            }

            float cv[16];
            float score = 0.f;
            #pragma unroll
            for (int d = 0; d < 16; ++d) {
                float s2 = A[r][hl * 32 + d] * A[r][hl * 32 + 16 + d];
                float sq = (s2 >= 0.f) ? sqrtf(s2) : -sqrtf(-s2);
                float c  = kq[d] + sq;
                cv[d] = c;
                score += c * Aw[d * NH + h];
            }
            float4* co = (float4*)(conn_out + (size_t)e * OUTD + h * HD);
            #pragma unroll
            for (int i = 0; i < 4; ++i)
                co[i] = make_float4(cv[i * 4 + 0], cv[i * 4 + 1],
                                    cv[i * 4 + 2], cv[i * 4 + 3]);

            score = fminf(fmaxf(score, -CLAMP_V), CLAMP_V);
            float ex = expf(score);          // clamp => no overflow; max-sub not needed
            exp_s[(size_t)e * NH + h] = ex;
            atomicAdd(&denom[(size_t)dst * NH + h], ex);
        }
    }
}

// ---------------------------------------------------------------------------
// Kernel 3: scatter pass.  2 edges per 256-thread block.
// attn = exp/denom; atomicAdd Vh[src]*attn into Vo, conn*attn into rowV.
// ---------------------------------------------------------------------------
__global__ __launch_bounds__(256) void scatter_kernel(
    const int*   __restrict__ edge_index,
    const float* __restrict__ Vh,
    const float* __restrict__ conn,
    const float* __restrict__ exp_s,
    const float* __restrict__ denom,
    float* __restrict__ Vo,
    float* __restrict__ rowV)
{
    const int t = threadIdx.x;
    const int e = blockIdx.x * 2 + (t >> 7);
    const int c = t & 127;
    const int h = c >> 4;

    const int src = edge_index[e];
    const int dst = edge_index[N_EDGES + e];

    const float attn = exp_s[(size_t)e * NH + h] /
                       (denom[(size_t)dst * NH + h] + 1e-16f);

    const float mv = Vh[(size_t)src * OUTD + c] * attn;
    atomicAdd(&Vo[(size_t)dst * OUTD + c], mv);
    const float rv = conn[(size_t)e * OUTD + c] * attn;
    atomicAdd(&rowV[(size_t)dst * OUTD + c], rv);
}

// ---------------------------------------------------------------------------
// Kernel 4: finalize.  Vo[n,h,c] += sum_d rowV[n,h,d] * VeRow[d,h,c].
// 2 nodes per 256-thread block; VeRow (8 KB) cached in LDS.
// ---------------------------------------------------------------------------
__global__ __launch_bounds__(256) void finalize_kernel(
    const float* __restrict__ rowV,
    const float* __restrict__ VeRow,
    float* __restrict__ Vo)
{
    __shared__ float ver[2048];
    __shared__ float rv[256];
    const int t = threadIdx.x;

    #pragma unroll
    for (int it = 0; it < 2; ++it) {
        int idx = it * 256 + t;
        *(float4*)&ver[idx * 4] = *(const float4*)&VeRow[idx * 4];
    }
    const int n0 = blockIdx.x * 2;
    if (t < 64)
        *(float4*)&rv[t * 4] = *(const float4*)&rowV[(size_t)n0 * OUTD + t * 4];
    __syncthreads();

    const int nl = t >> 7, c = t & 127, h = c >> 4, cc = c & 15;
    float acc = 0.f;
    #pragma unroll
    for (int d = 0; d < 16; ++d)
        acc += rv[nl * 128 + h * 16 + d] * ver[d * 128 + h * 16 + cc];

    Vo[(size_t)(n0 + nl) * OUTD + c] += acc;
}

// ---------------------------------------------------------------------------
extern "C" void kernel_launch(void* const* d_in, const int* in_sizes, int n_in,
                              void* d_out, int out_size, void* d_ws, size_t ws_size,
                              hipStream_t stream)
{
    const float* x         = (const float*)d_in[0];
    const float* edge_attr = (const float*)d_in[1];
    const int*   edge_index= (const int*)  d_in[2];
    const float* WQ = (const float*)d_in[3];
    const float* bQ = (const float*)d_in[4];
    const float* WK = (const float*)d_in[5];
    const float* bK = (const float*)d_in[6];
    const float* WE = (const float*)d_in[7];
    const float* bE = (const float*)d_in[8];
    const float* WV = (const float*)d_in[9];
    const float* bV = (const float*)d_in[10];
    const float* Aw = (const float*)d_in[11];
    const float* VeRow = (const float*)d_in[12];

    float* Vo   = (float*)d_out;                       // [N,128]
    float* conn = Vo + (size_t)N_NODES * OUTD;         // [E,128]

    float* ws    = (float*)d_ws;
    float* Kh    = ws;                                 // N*128
    float* Vh    = Kh   + (size_t)N_NODES * OUTD;      // N*128
    float* rowV  = Vh   + (size_t)N_NODES * OUTD;      // N*128
    float* denom = rowV + (size_t)N_NODES * OUTD;      // N*8
    float* exp_s = denom+ (size_t)N_NODES * NH;        // E*8

    hipMemsetAsync(rowV,  0, (size_t)N_NODES * OUTD * sizeof(float), stream);
    hipMemsetAsync(denom, 0, (size_t)N_NODES * NH   * sizeof(float), stream);

    dim3 g1((N_NODES + 63) / 64, 6);
    node_gemm_kernel<<<g1, 256, 0, stream>>>(x, WQ, bQ, WK, bK, WV, bV, Vo, Kh, Vh);

    dim3 g2((N_EDGES + 63) / 64, 4);
    edge_kernel<<<g2, 256, 0, stream>>>(edge_attr, edge_index, WE, bE, Aw,
                                        Vo, Kh, conn, exp_s, denom);

    scatter_kernel<<<N_EDGES / 2, 256, 0, stream>>>(edge_index, Vh, conn,
                                                    exp_s, denom, Vo, rowV);

    finalize_kernel<<<N_NODES / 2, 256, 0, stream>>>(rowV, VeRow, Vo);
}